// Round 12
// baseline (83.819 us; speedup 1.0000x reference)
//
#include <hip/hip_runtime.h>

#define NB_BS   2048
#define NB_NINP 512
#define NB_NHID 512
#define NB_K    16
#define NB_T    8
#define NB_M    32
#define NB_C    768   // T * 3 * M
#define H_OUT_ELEMS (NB_BS * NB_NHID)   // 1048576
#define GI_ELEMS (NB_BS * NB_C)         // 1572864

// ---------------------------------------------------------------------------
// Kernel 1 (partial): gp[kz][b][c] = sum_{i in K-slice kz} x[b][i]*Wih[c][i]
//                     (+ bias when kz == 0)
// 64x96 tile, 256 threads, K-SPLIT-4 ACROSS BLOCKS: grid (32,8,4) = 1024
// blocks = 4 independent blocks/CU = 4 waves/SIMD with PRIVATE barriers
// (r11 put the 4 K-groups in one 1024-thr block -> 16-wave lockstep at every
// slab barrier; this decouples them). Proven 4x6 micro: av = 4-addr
// broadcast b128, wv = 3 conflict-free b64 (6*cg mod 32 distinct).
// K-slice 128, BK=32 -> 4 slabs, single-buffer, register prefetch.
// k2 sums the 4 partials in fixed z order => deterministic (no atomics).
// ---------------------------------------------------------------------------
__global__ __launch_bounds__(256, 4)
void k1_part(const float* __restrict__ x, const float* __restrict__ Wih,
             const float* __restrict__ bih, const float* __restrict__ bhh,
             float* __restrict__ gp)
{
    __shared__ __align__(16) float As[32][68];    // [k][row]  8.7 KB
    __shared__ __align__(16) float Bs[32][100];   // [k][col] 12.8 KB

    const int tid  = threadIdx.x;
    const int row0 = blockIdx.x * 64;
    const int col0 = blockIdx.y * 96;
    const int kz   = blockIdx.z;
    const int kb0  = kz * 128;
    const int rg   = tid >> 4;            // 0..15 -> rows rg*4..+3 (4/wave)
    const int cg   = tid & 15;            // 0..15 -> cols cg*6..+5

    // A staging: 2 f4/thread (64 rows x 8 k-quads); B: 3 f4/thread (96 cols)
    const int ar0 = tid >> 3, akq = (tid & 7) * 4, ar1 = ar0 + 32;
    const int c0 = tid >> 3, c1 = c0 + 32, c2 = c0 + 64;

    float4 a0 = *(const float4*)&x[(size_t)(row0 + ar0) * NB_NINP + kb0 + akq];
    float4 a1 = *(const float4*)&x[(size_t)(row0 + ar1) * NB_NINP + kb0 + akq];
    float4 b0 = *(const float4*)&Wih[(size_t)(col0 + c0) * NB_NINP + kb0 + akq];
    float4 b1 = *(const float4*)&Wih[(size_t)(col0 + c1) * NB_NINP + kb0 + akq];
    float4 b2 = *(const float4*)&Wih[(size_t)(col0 + c2) * NB_NINP + kb0 + akq];

    float acc[4][6];
    #pragma unroll
    for (int i = 0; i < 4; ++i)
        #pragma unroll
        for (int e = 0; e < 6; ++e) acc[i][e] = 0.f;

    for (int slab = 0; slab < 4; ++slab) {         // 4 slabs of BK=32
        __syncthreads();
        As[akq+0][ar0]=a0.x; As[akq+1][ar0]=a0.y;
        As[akq+2][ar0]=a0.z; As[akq+3][ar0]=a0.w;
        As[akq+0][ar1]=a1.x; As[akq+1][ar1]=a1.y;
        As[akq+2][ar1]=a1.z; As[akq+3][ar1]=a1.w;
        Bs[akq+0][c0]=b0.x; Bs[akq+1][c0]=b0.y;
        Bs[akq+2][c0]=b0.z; Bs[akq+3][c0]=b0.w;
        Bs[akq+0][c1]=b1.x; Bs[akq+1][c1]=b1.y;
        Bs[akq+2][c1]=b1.z; Bs[akq+3][c1]=b1.w;
        Bs[akq+0][c2]=b2.x; Bs[akq+1][c2]=b2.y;
        Bs[akq+2][c2]=b2.z; Bs[akq+3][c2]=b2.w;
        __syncthreads();
        if (slab < 3) {   // prefetch next slab of this K-slice
            const int kb = kb0 + (slab + 1) * 32;
            a0 = *(const float4*)&x[(size_t)(row0 + ar0) * NB_NINP + kb + akq];
            a1 = *(const float4*)&x[(size_t)(row0 + ar1) * NB_NINP + kb + akq];
            b0 = *(const float4*)&Wih[(size_t)(col0 + c0) * NB_NINP + kb + akq];
            b1 = *(const float4*)&Wih[(size_t)(col0 + c1) * NB_NINP + kb + akq];
            b2 = *(const float4*)&Wih[(size_t)(col0 + c2) * NB_NINP + kb + akq];
        }
        #pragma unroll
        for (int kk = 0; kk < 32; ++kk) {
            const float4 av = *(const float4*)&As[kk][rg * 4];   // 4-addr bc
            const float2 w0 = *(const float2*)&Bs[kk][cg * 6];
            const float2 w1 = *(const float2*)&Bs[kk][cg * 6 + 2];
            const float2 w2 = *(const float2*)&Bs[kk][cg * 6 + 4];
            const float avv[4] = {av.x, av.y, av.z, av.w};
            const float wvv[6] = {w0.x, w0.y, w1.x, w1.y, w2.x, w2.y};
            #pragma unroll
            for (int i = 0; i < 4; ++i)
                #pragma unroll
                for (int e = 0; e < 6; ++e)
                    acc[i][e] = fmaf(avv[i], wvv[e], acc[i][e]);
        }
    }

    float bias[6];
    #pragma unroll
    for (int e = 0; e < 6; ++e) {
        const int cl = cg * 6 + e;        // c % 96
        const int c  = col0 + cl;
        bias[e] = (kz == 0) ? (bih[c] + (cl < 64 ? bhh[c] : 0.f)) : 0.f;
    }
    float* go = gp + (size_t)kz * GI_ELEMS;
    #pragma unroll
    for (int i = 0; i < 4; ++i) {
        const size_t base = (size_t)(row0 + rg * 4 + i) * NB_C + col0 + cg * 6;
        #pragma unroll
        for (int e = 0; e < 6; e += 2) {
            float2 o;
            o.x = acc[i][e]   + bias[e];
            o.y = acc[i][e+1] + bias[e+1];
            *(float2*)&go[base + e] = o;
        }
    }
}

// ---------------------------------------------------------------------------
// Kernel 1 fallback (r11 verbatim): used only if ws_size < 24 MB.
// 64x96 tile, 1024 threads, K-split-4 inside the block, ACCX combine.
// ---------------------------------------------------------------------------
__global__ __launch_bounds__(1024)
void k1_gemm_gi(const float* __restrict__ x, const float* __restrict__ Wih,
                const float* __restrict__ bih, const float* __restrict__ bhh,
                float* __restrict__ gi)
{
    __shared__ __align__(16) float As[4][16][68];
    __shared__ __align__(16) float Bs[4][16][100];
    __shared__ float ACCX[256][25];

    const int tid  = threadIdx.x;
    const int kg   = tid >> 8;
    const int ttid = tid & 255;
    const int row0 = blockIdx.x * 64;
    const int col0 = blockIdx.y * 96;
    const int rg   = ttid >> 4;
    const int cg   = ttid & 15;
    const int kb0  = kg * 128;

    const int ar = ttid >> 2, akq = (ttid & 3) * 4;
    const int bc0 = ttid >> 2,         bk0 = (ttid & 3) * 4;
    const int bc1 = (256 + ttid) >> 2, bk1 = (ttid & 3) * 4;

    float4 a0 = *(const float4*)&x[(size_t)(row0 + ar) * NB_NINP + kb0 + akq];
    float4 b0 = *(const float4*)&Wih[(size_t)(col0 + bc0) * NB_NINP + kb0 + bk0];
    float4 b1;
    if (ttid < 128)
        b1 = *(const float4*)&Wih[(size_t)(col0 + bc1) * NB_NINP + kb0 + bk1];

    float acc[4][6];
    #pragma unroll
    for (int i = 0; i < 4; ++i)
        #pragma unroll
        for (int e = 0; e < 6; ++e) acc[i][e] = 0.f;

    for (int slab = 0; slab < 8; ++slab) {
        __syncthreads();
        As[kg][akq+0][ar]=a0.x; As[kg][akq+1][ar]=a0.y;
        As[kg][akq+2][ar]=a0.z; As[kg][akq+3][ar]=a0.w;
        Bs[kg][bk0+0][bc0]=b0.x; Bs[kg][bk0+1][bc0]=b0.y;
        Bs[kg][bk0+2][bc0]=b0.z; Bs[kg][bk0+3][bc0]=b0.w;
        if (ttid < 128) {
            Bs[kg][bk1+0][bc1]=b1.x; Bs[kg][bk1+1][bc1]=b1.y;
            Bs[kg][bk1+2][bc1]=b1.z; Bs[kg][bk1+3][bc1]=b1.w;
        }
        __syncthreads();
        if (slab < 7) {
            const int kb = kb0 + (slab + 1) * 16;
            a0 = *(const float4*)&x[(size_t)(row0 + ar) * NB_NINP + kb + akq];
            b0 = *(const float4*)&Wih[(size_t)(col0 + bc0) * NB_NINP + kb + bk0];
            if (ttid < 128)
                b1 = *(const float4*)&Wih[(size_t)(col0 + bc1) * NB_NINP + kb + bk1];
        }
        #pragma unroll
        for (int kk = 0; kk < 16; ++kk) {
            const float4 av = *(const float4*)&As[kg][kk][rg * 4];
            const float2 w0 = *(const float2*)&Bs[kg][kk][cg * 6];
            const float2 w1 = *(const float2*)&Bs[kg][kk][cg * 6 + 2];
            const float2 w2 = *(const float2*)&Bs[kg][kk][cg * 6 + 4];
            const float avv[4] = {av.x, av.y, av.z, av.w};
            const float wvv[6] = {w0.x, w0.y, w1.x, w1.y, w2.x, w2.y};
            #pragma unroll
            for (int i = 0; i < 4; ++i)
                #pragma unroll
                for (int e = 0; e < 6; ++e)
                    acc[i][e] = fmaf(avv[i], wvv[e], acc[i][e]);
        }
    }

    #pragma unroll 1
    for (int src = 1; src < 4; ++src) {
        __syncthreads();
        if (kg == src) {
            #pragma unroll
            for (int i = 0; i < 4; ++i)
                #pragma unroll
                for (int e = 0; e < 6; ++e) ACCX[ttid][i * 6 + e] = acc[i][e];
        }
        __syncthreads();
        if (kg == 0) {
            #pragma unroll
            for (int i = 0; i < 4; ++i)
                #pragma unroll
                for (int e = 0; e < 6; ++e) acc[i][e] += ACCX[ttid][i * 6 + e];
        }
    }
    if (kg == 0) {
        float bias[6];
        #pragma unroll
        for (int e = 0; e < 6; ++e) {
            const int cl = cg * 6 + e;
            const int c  = col0 + cl;
            bias[e] = bih[c] + (cl < 64 ? bhh[c] : 0.f);
        }
        #pragma unroll
        for (int i = 0; i < 4; ++i) {
            const size_t base = (size_t)(row0 + rg * 4 + i) * NB_C + col0 + cg * 6;
            #pragma unroll
            for (int e = 0; e < 6; e += 2) {
                float2 o;
                o.x = acc[i][e]   + bias[e];
                o.y = acc[i][e+1] + bias[e+1];
                *(float2*)&gi[base + e] = o;
            }
        }
    }
}

// ---------------------------------------------------------------------------
// Kernel 2: fused gh-GEMM + GRU + write-key logits + gumbel-argmax + gather.
// r11 verbatim (50.4us / 60 VGPR / no spill) except gi_r sums nz partial
// slabs of gi (fixed z order -> deterministic).
// ---------------------------------------------------------------------------
__global__ __launch_bounds__(1024)
__attribute__((amdgpu_waves_per_eu(4, 4)))
void k2_fused(const float* __restrict__ h,      const float* __restrict__ Whh,
              const float* __restrict__ bhh,    const float* __restrict__ wread,
              const float* __restrict__ wwrite, const float* __restrict__ gumb,
              const float* __restrict__ gi,     const int nz,
              float* __restrict__ out)
{
    __shared__ __align__(16) float4 P[3][32][64];   // 98304 B  W_hh planes
    __shared__ __align__(16) float4 WWT4[16][64];   // 16384 B
    __shared__ __align__(16) float WR[512];         //  2048 B
    __shared__ __align__(16) float HT[8][32][20];   // 20480 B  [bl][m][k]
    __shared__ __align__(16) float HR2T[8][16][20]; // 10240 B  [bl][f][k]
    __shared__ __align__(16) float LG[8][16][8];    //  4096 B  [bl][k][t]

    const int tid  = threadIdx.x;
    const int wave = tid >> 6, lane = tid & 63;
    const int bl   = wave >> 1, kh = wave & 1;
    const int b    = blockIdx.x * 8 + bl;
    const int m_   = lane & 31, half = lane >> 5;

    float* PF = (float*)P;
    for (int i = tid; i < 24576; i += 1024) {       // Whh flat [c][m]
        const int c = i >> 5, mm = i & 31;
        const int t = c / 96, rem = c - t * 96;
        const int gc = rem >> 5, mout = rem & 31;
        const int j  = (t >> 1) * 3 + gc;
        const int sl = ((t & 1) * 32 + mout) ^ (mm & 7);
        PF[(((j >> 2) * 32 + mm) * 64 + sl) * 4 + (j & 3)] = Whh[i];
    }
    for (int i = tid; i < 4096; i += 1024) {        // wwrite flat [t][m][f]
        const int t = i >> 9, mo = (i >> 4) & 31, f = i & 15;
        ((float*)WWT4)[(f * 64 + (t & 1) * 32 + mo) * 4 + (t >> 1)] = wwrite[i];
    }
    if (tid < 512) WR[tid] = wread[tid];
    #pragma unroll
    for (int e = 0; e < 4; ++e) {
        const int idx = kh * 256 + e * 64 + lane;
        HT[bl][idx & 31][idx >> 5] = h[(size_t)b * NB_NHID + idx];
    }
    __syncthreads();   // only barrier; everything below is wave-local

    {
        const int kq = kh * 8 + (lane >> 3);
        const int f0 = (lane & 7) * 2;
        float s0 = 0.f, s1 = 0.f;
        #pragma unroll 8
        for (int mm = 0; mm < 32; ++mm) {
            const float hv = HT[bl][mm][kq];
            s0 = fmaf(hv, WR[mm * 16 + f0], s0);
            s1 = fmaf(hv, WR[mm * 16 + f0 + 1], s1);
        }
        HR2T[bl][f0    ][kq] = s0;
        HR2T[bl][f0 + 1][kq] = s1;
    }

    // ---- per-lane gi' = sum of nz partials (+ bias folded in z==0 by k1)
    float gi_r[4][3], bhn[4];
    #pragma unroll
    for (int p = 0; p < 4; ++p) {
        #pragma unroll
        for (int gc = 0; gc < 3; ++gc) gi_r[p][gc] = 0.f;
        bhn[p] = bhh[(2 * p + half) * 96 + 64 + m_];
    }
    for (int z = 0; z < nz; ++z) {
        const float* g = gi + (size_t)z * GI_ELEMS + (size_t)b * NB_C;
        #pragma unroll
        for (int p = 0; p < 4; ++p)
            #pragma unroll
            for (int gc = 0; gc < 3; ++gc)
                gi_r[p][gc] += g[(2 * p + half) * 96 + gc * 32 + m_];
    }

    #pragma unroll 1
    for (int pass = 0; pass < 2; ++pass) {
        const int k0 = kh * 8 + pass * 4;

        float acc[4][12];
        #pragma unroll
        for (int r = 0; r < 4; ++r)
            #pragma unroll
            for (int j = 0; j < 12; ++j) acc[r][j] = 0.f;

        __builtin_amdgcn_s_setprio(1);
        #pragma unroll 4
        for (int mm = 0; mm < 32; ++mm) {
            const int sw = lane ^ (mm & 7);
            const float4 w0 = P[0][mm][sw];
            const float4 w1 = P[1][mm][sw];
            const float4 w2 = P[2][mm][sw];
            const float4 hv = *(const float4*)&HT[bl][mm][k0];   // broadcast
            const float wj[12] = {w0.x,w0.y,w0.z,w0.w, w1.x,w1.y,w1.z,w1.w,
                                  w2.x,w2.y,w2.z,w2.w};
            const float hr4[4] = {hv.x, hv.y, hv.z, hv.w};
            #pragma unroll
            for (int r = 0; r < 4; ++r)
                #pragma unroll
                for (int j = 0; j < 12; ++j)
                    acc[r][j] = fmaf(hr4[r], wj[j], acc[r][j]);
        }
        __builtin_amdgcn_s_setprio(0);

        float ww[4][4];
        #pragma unroll
        for (int r = 0; r < 4; ++r)
            #pragma unroll
            for (int p = 0; p < 4; ++p) ww[r][p] = 0.f;
        #pragma unroll 4
        for (int f = 0; f < 16; ++f) {
            const float4 wt4 = WWT4[f][half * 32 + m_];           // b128 spread
            const float4 hka = *(const float4*)&HR2T[bl][f][k0];  // broadcast
            const float wt[4] = {wt4.x, wt4.y, wt4.z, wt4.w};
            const float hk[4] = {hka.x, hka.y, hka.z, hka.w};
            #pragma unroll
            for (int r = 0; r < 4; ++r)
                #pragma unroll
                for (int p = 0; p < 4; ++p)
                    ww[r][p] = fmaf(hk[r], wt[p], ww[r][p]);
        }

        #pragma unroll
        for (int r = 0; r < 4; ++r) {
            const int k = k0 + r;
            const float h2v = HT[bl][m_][k];
            float hn[4], part[4];
            #pragma unroll
            for (int p = 0; p < 4; ++p) {
                const float xr = gi_r[p][0] + acc[r][p*3+0];
                const float xz = gi_r[p][1] + acc[r][p*3+1];
                const float gn = bhn[p]     + acc[r][p*3+2];
                const float rg = 1.f / (1.f + __expf(-xr));
                const float zg = 1.f / (1.f + __expf(-xz));
                const float xn = gi_r[p][2] + rg * gn;
                const float e2 = __expf(2.f * xn);
                const float tn = 1.f - 2.f / (e2 + 1.f);   // tanh
                const float hv2 = (1.f - zg) * tn + zg * h2v;
                hn[p] = hv2;
                part[p] = hv2 * ww[r][p];
            }
            #pragma unroll
            for (int p = 0; p < 4; ++p)
                part[p] += __shfl_xor(part[p], 16, 64);
            const bool b4 = (lane & 16) != 0, b3 = (lane & 8) != 0;
            float v01 = b4 ? part[1] : part[0];
            float v23 = b4 ? part[3] : part[2];
            v01 += __shfl_xor(v01, 8, 64);
            v23 += __shfl_xor(v23, 8, 64);
            float v = b3 ? v23 : v01;
            v += __shfl_xor(v, 4, 64);
            v += __shfl_xor(v, 2, 64);
            v += __shfl_xor(v, 1, 64);
            if ((lane & 7) == 0) {
                const int p_ = ((lane >> 4) & 1) | (((lane >> 3) & 1) << 1);
                LG[bl][k][2 * p_ + half] = v;
            }
            const float4 l0 = *(const float4*)&LG[bl][k][0];   // broadcast
            const float4 l1 = *(const float4*)&LG[bl][k][4];
            const float* gp = gumb + ((size_t)b * NB_K + k) * NB_T;
            const float4 ga = *(const float4*)gp;
            const float4 gb = *(const float4*)(gp + 4);
            const float s[8] = {l0.x+ga.x, l0.y+ga.y, l0.z+ga.z, l0.w+ga.w,
                                l1.x+gb.x, l1.y+gb.y, l1.z+gb.z, l1.w+gb.w};
            float best = s[0]; int bt = 0;
            #pragma unroll
            for (int t2 = 1; t2 < 8; ++t2)
                if (s[t2] > best) { best = s[t2]; bt = t2; }   // first-max
            const int pstar = bt >> 1, hstar = bt & 1;
            float hsel = hn[0];
            hsel = (pstar == 1) ? hn[1] : hsel;
            hsel = (pstar == 2) ? hn[2] : hsel;
            hsel = (pstar == 3) ? hn[3] : hsel;
            if (half == hstar)
                out[(size_t)b * NB_NHID + k * 32 + m_] = hsel;
            if (lane < 8)
                out[H_OUT_ELEMS + ((size_t)b * NB_K + k) * NB_T + lane] =
                    (lane == bt) ? 1.f : 0.f;
        }
    }
}

extern "C" void kernel_launch(void* const* d_in, const int* in_sizes, int n_in,
                              void* d_out, int out_size, void* d_ws, size_t ws_size,
                              hipStream_t stream) {
    const float* x      = (const float*)d_in[0];
    const float* h      = (const float*)d_in[1];
    const float* Wih    = (const float*)d_in[2];
    const float* Whh    = (const float*)d_in[3];
    const float* bih    = (const float*)d_in[4];
    const float* bhh    = (const float*)d_in[5];
    const float* wread  = (const float*)d_in[6];
    const float* wwrite = (const float*)d_in[7];
    const float* gumb   = (const float*)d_in[8];
    float* out = (float*)d_out;
    float* gi  = (float*)d_ws;

    const bool split = (ws_size >= (size_t)4 * GI_ELEMS * sizeof(float));
    if (split) {
        k1_part<<<dim3(32, 8, 4), 256, 0, stream>>>(x, Wih, bih, bhh, gi);
        k2_fused<<<dim3(256), 1024, 0, stream>>>(h, Whh, bhh, wread, wwrite,
                                                 gumb, gi, 4, out);
    } else {
        k1_gemm_gi<<<dim3(32, 8), 1024, 0, stream>>>(x, Wih, bih, bhh, gi);
        k2_fused<<<dim3(256), 1024, 0, stream>>>(h, Whh, bhh, wread, wwrite,
                                                 gumb, gi, 1, out);
    }
}